// Round 11
// baseline (1294.346 us; speedup 1.0000x reference)
//
#include <hip/hip_runtime.h>
#include <hip/hip_bf16.h>

// Grouped SwiGLU experts: E=8, T=2048, D_IN=2048, D_H=5632. FP32 in/out.
// r15: r14 (128x128 gu, 2 blocks/CU -> MfmaUtil 49->52) + FETCH fix: block
// map groups 64 co-resident blocks (one XCD's full complement) as 16M x 4N,
// so X-panel sharers run concurrently (single L2/L3 fetch) instead of being
// spread across the kernel lifetime (r14: +340MB HBM X re-reads).
// gemm_out/transposes/conv unchanged (r13-verified).

#define NEXP 8
#define TT   2048
#define DIN  2048
#define DH   5632

using short8 = __attribute__((ext_vector_type(8))) short;   // 8 x bf16
using f32x4  = __attribute__((ext_vector_type(4))) float;   // MFMA acc

static __device__ __forceinline__ unsigned short f2bf(float f) {
    unsigned int i = __float_as_uint(f);
    return (unsigned short)((i + 0x7FFFu + ((i >> 16) & 1u)) >> 16);  // RNE
}
static __device__ __forceinline__ void gld16(const void* g, void* l) {
    __builtin_amdgcn_global_load_lds(
        (const __attribute__((address_space(1))) void*)g,
        (__attribute__((address_space(3))) void*)l, 16, 0, 0);
}

// ---------------------------------------------------------------------------
// Fused G/U GEMM: 128x128 tile, BK=64, 4 waves (2M x 2N; wave = 64x64 per
// matrix). LDS ring-5 x 16KB units; unit(t): A=(3t)%5, G=(3t+1)%5, D=(3t+2)%5.
// Per step: P0 read A(8)+G01(4), stage A,G(t+1), lgkm, MFMA G n01, vmcnt(8),
// MID-BARRIER, stage D(t+1)->A(t) slot; P1 read G23, MFMA G n23; P2 read D01,
// MFMA U n01; P3 read D23, MFMA U n23, vmcnt(4), END-BARRIER.
// Block map: e=bid&7 (XCD); w=bid>>3; g=w>>6, r=w&63 -> 64-block co-resident
// groups of 16M x 4N (X-panel: 4 concurrent readers; W-panel: 16 concurrent).
// ---------------------------------------------------------------------------
__global__ __launch_bounds__(256, 2) void gemm_gu(
    const unsigned short* __restrict__ Xb,   // [E][T][DIN] bf16
    const unsigned short* __restrict__ Wgt,  // [E][DH][DIN] bf16 (K-major)
    const unsigned short* __restrict__ Wdt,  // [E][DH][DIN] bf16
    unsigned short* __restrict__ Hb)         // [E][T][DH] bf16
{
    __shared__ __align__(16) unsigned short lds[40960];  // 80 KB = 5 x 16 KB

    const int tid  = threadIdx.x;
    const int wave = tid >> 6, lane = tid & 63;
    const int l15 = lane & 15, l4 = lane >> 4;
    const int wr = wave >> 1, wc = wave & 1;     // 2M x 2N wave grid

    const int bid = blockIdx.x;                  // 5632 = 8 * 704
    const int e   = bid & 7;                     // expert == XCD
    const int w   = bid >> 3;                    // [0,704)
    const int gq  = w >> 6;                      // group [0,11)
    const int rr  = w & 63;                      // in-group
    const int m0  = (rr & 15) * 128;
    const int n0  = (gq * 4 + (rr >> 4)) * 128;

    const int K = DIN, NT = DIN >> 6;            // NT = 32

    const unsigned short* Ae = Xb  + (size_t)e * TT * DIN + (size_t)m0 * K;
    const unsigned short* Gp = Wgt + (size_t)e * DH * DIN + (size_t)n0 * K;
    const unsigned short* Dp = Wdt + (size_t)e * DH * DIN + (size_t)n0 * K;
    unsigned short* He = Hb + (size_t)e * TT * DH;

    // Stage-side: 1024 16B-chunks/unit; chunk c = k*256 + tid, k=0..3.
    // Source pre-swizzle cs = c ^ ((c>>3)&7) (r5-verified pair with read XOR).
    size_t loff[4];
    int dofs[4];
#pragma unroll
    for (int k = 0; k < 4; ++k) {
        const int c = k * 256 + tid;
        const int cs = c ^ ((c >> 3) & 7);
        loff[k] = (size_t)(cs >> 3) * K + (cs & 7) * 8;
        dofs[k] = k * 4096 + wave * 1024;
    }

    // Read-side swizzled byte offsets within a 16KB [128][64] unit.
    int ibA[4][2], ibB[4][2];
#pragma unroll
    for (int s = 0; s < 4; ++s)
#pragma unroll
        for (int ks = 0; ks < 2; ++ks) {
            const int rA = wr * 64 + s * 16 + l15;
            ibA[s][ks] = (rA * 128 + ks * 64 + l4 * 16) ^ ((rA & 7) << 4);
            const int rB = wc * 64 + s * 16 + l15;
            ibB[s][ks] = (rB * 128 + ks * 64 + l4 * 16) ^ ((rB & 7) << 4);
        }

    f32x4 accG[4][4] = {}, accU[4][4] = {};      // [m-frag][n-frag]
    short8 Aq[4][2], Bq[2][2];

    char* ldsb = (char*)lds;
    const char* ldsc = (const char*)lds;
    auto stageU = [&](const unsigned short* p, int kk, int slot) {
#pragma unroll
        for (int k = 0; k < 4; ++k)
            gld16(p + kk + loff[k], ldsb + slot * 16384 + dofs[k]);
    };
    auto w5 = [](int x) { return x >= 5 ? x - 5 : x; };

    // Prologue: A(0)->0, G(0)->1, D(0)->2.
    stageU(Ae, 0, 0); stageU(Gp, 0, 1); stageU(Dp, 0, 2);
    asm volatile("s_waitcnt vmcnt(0)" ::: "memory");
    asm volatile("s_barrier" ::: "memory");

    int q = 0;                                   // (3t) % 5
    for (int t = 0; t < NT; ++t) {
        const int bA = q * 16384;
        const int bG = w5(q + 1) * 16384;
        const int bD = w5(q + 2) * 16384;
        const int stA = w5(q + 3);               // A(t+1): G(t-1)'s slot, stale
        const int stG = w5(q + 4);               // G(t+1): D(t-1)'s slot, stale

        // P0: read A(8) + G s01(4); stage A,G(t+1); MFMA G n=0,1.
#pragma unroll
        for (int s = 0; s < 4; ++s) {
            Aq[s][0] = *(const short8*)(ldsc + bA + ibA[s][0]);
            Aq[s][1] = *(const short8*)(ldsc + bA + ibA[s][1]);
        }
#pragma unroll
        for (int s = 0; s < 2; ++s) {
            Bq[s][0] = *(const short8*)(ldsc + bG + ibB[s][0]);
            Bq[s][1] = *(const short8*)(ldsc + bG + ibB[s][1]);
        }
        if (t + 1 < NT) {
            stageU(Ae, (t + 1) * 64, stA);
            stageU(Gp, (t + 1) * 64, stG);
        }
        asm volatile("s_waitcnt lgkmcnt(0)" ::: "memory");
        __builtin_amdgcn_sched_barrier(0);
        __builtin_amdgcn_s_setprio(1);
#pragma unroll
        for (int m = 0; m < 4; ++m)
#pragma unroll
            for (int n = 0; n < 2; ++n) {
                accG[m][n] = __builtin_amdgcn_mfma_f32_16x16x32_bf16(Aq[m][0], Bq[n][0], accG[m][n], 0, 0, 0);
                accG[m][n] = __builtin_amdgcn_mfma_f32_16x16x32_bf16(Aq[m][1], Bq[n][1], accG[m][n], 0, 0, 0);
            }
        __builtin_amdgcn_s_setprio(0);
        // Drain D(t) per-wave (oldest 4 of the 12 in flight), then globalize.
        asm volatile("s_waitcnt vmcnt(8)" ::: "memory");
        asm volatile("s_barrier" ::: "memory");  // MID: A(t)-reads + D(t) done
        if (t + 1 < NT) stageU(Dp, (t + 1) * 64, q);   // turnaround -> A(t) slot

        // P1: read G s23; MFMA G n=2,3.
#pragma unroll
        for (int s = 0; s < 2; ++s) {
            Bq[s][0] = *(const short8*)(ldsc + bG + ibB[2 + s][0]);
            Bq[s][1] = *(const short8*)(ldsc + bG + ibB[2 + s][1]);
        }
        asm volatile("s_waitcnt lgkmcnt(0)" ::: "memory");
        __builtin_amdgcn_sched_barrier(0);
        __builtin_amdgcn_s_setprio(1);
#pragma unroll
        for (int m = 0; m < 4; ++m)
#pragma unroll
            for (int n = 0; n < 2; ++n) {
                accG[m][2 + n] = __builtin_amdgcn_mfma_f32_16x16x32_bf16(Aq[m][0], Bq[n][0], accG[m][2 + n], 0, 0, 0);
                accG[m][2 + n] = __builtin_amdgcn_mfma_f32_16x16x32_bf16(Aq[m][1], Bq[n][1], accG[m][2 + n], 0, 0, 0);
            }
        __builtin_amdgcn_s_setprio(0);

        // P2: read D s01; MFMA U n=0,1.
#pragma unroll
        for (int s = 0; s < 2; ++s) {
            Bq[s][0] = *(const short8*)(ldsc + bD + ibB[s][0]);
            Bq[s][1] = *(const short8*)(ldsc + bD + ibB[s][1]);
        }
        asm volatile("s_waitcnt lgkmcnt(0)" ::: "memory");
        __builtin_amdgcn_sched_barrier(0);
        __builtin_amdgcn_s_setprio(1);
#pragma unroll
        for (int m = 0; m < 4; ++m)
#pragma unroll
            for (int n = 0; n < 2; ++n) {
                accU[m][n] = __builtin_amdgcn_mfma_f32_16x16x32_bf16(Aq[m][0], Bq[n][0], accU[m][n], 0, 0, 0);
                accU[m][n] = __builtin_amdgcn_mfma_f32_16x16x32_bf16(Aq[m][1], Bq[n][1], accU[m][n], 0, 0, 0);
            }
        __builtin_amdgcn_s_setprio(0);

        // P3: read D s23; MFMA U n=2,3; counted vmcnt; end barrier.
#pragma unroll
        for (int s = 0; s < 2; ++s) {
            Bq[s][0] = *(const short8*)(ldsc + bD + ibB[2 + s][0]);
            Bq[s][1] = *(const short8*)(ldsc + bD + ibB[2 + s][1]);
        }
        asm volatile("s_waitcnt lgkmcnt(0)" ::: "memory");
        __builtin_amdgcn_sched_barrier(0);
        __builtin_amdgcn_s_setprio(1);
#pragma unroll
        for (int m = 0; m < 4; ++m)
#pragma unroll
            for (int n = 0; n < 2; ++n) {
                accU[m][2 + n] = __builtin_amdgcn_mfma_f32_16x16x32_bf16(Aq[m][0], Bq[n][0], accU[m][2 + n], 0, 0, 0);
                accU[m][2 + n] = __builtin_amdgcn_mfma_f32_16x16x32_bf16(Aq[m][1], Bq[n][1], accU[m][2 + n], 0, 0, 0);
            }
        __builtin_amdgcn_s_setprio(0);
        if (t < NT - 2)       asm volatile("s_waitcnt vmcnt(4)" ::: "memory");
        else if (t == NT - 2) asm volatile("s_waitcnt vmcnt(0)" ::: "memory");
        asm volatile("s_barrier" ::: "memory");  // END: A,G(t+1) visible
        q = w5(q + 3);
    }

    // Epilogue: H = silu(G)*U. C/D: col = lane&15, row = (lane>>4)*4 + j.
#pragma unroll
    for (int m = 0; m < 4; ++m) {
        const int row_b = m0 + wr * 64 + m * 16 + l4 * 4;
#pragma unroll
        for (int n = 0; n < 4; ++n) {
            const int col = n0 + wc * 64 + n * 16 + l15;
#pragma unroll
            for (int j = 0; j < 4; ++j) {
                const float g = accG[m][n][j];
                const float u = accU[m][n][j];
                const float h = g / (1.f + __expf(-g)) * u;
                He[(size_t)(row_b + j) * DH + col] = f2bf(h);
            }
        }
    }
}

// ---------------------------------------------------------------------------
// Out-GEMM: Out = H * WuT^T, fp32 out. 256x256, BK=64, 8 waves (2Mx4N),
// ring-8 halves {A0,B0,B1,A1}, vmcnt(6)/K-tile. (r5-verified, unchanged.)
// ---------------------------------------------------------------------------
__global__ __launch_bounds__(512, 2) void gemm_out(
    const unsigned short* __restrict__ Ab,   // H [E][T][DH] bf16
    const unsigned short* __restrict__ Btb,  // WuT [E][DIN][DH] bf16
    float* __restrict__ Cf)                  // [E][T][DIN] fp32
{
    __shared__ __align__(16) unsigned short lds[65536];

    const int tid  = threadIdx.x;
    const int wave = tid >> 6, lane = tid & 63;
    const int l15 = lane & 15, l4 = lane >> 4;
    const int wr = wave >> 2, wc = wave & 3;     // 2M x 4N

    const int orig = blockIdx.x;                 // 512 = 8 * 64
    const int e    = orig & 7;
    const int w    = orig >> 3;                  // [0,64)
    const int r32  = w & 31;
    const int m0   = (r32 & 7) * 256;
    const int n0   = ((w >> 5) * 4 + (r32 >> 3)) * 256;

    const int N = DIN, K = DH, NT = K >> 6;      // NT = 88
    const unsigned short* Ae = Ab  + (size_t)e * TT * DH;
    const unsigned short* Be = Btb + (size_t)e * DIN * DH;

    const int c0 = tid, c1 = 512 + tid;
    const int cs0 = c0 ^ ((c0 >> 3) & 7), cs1 = c1 ^ ((c1 >> 3) & 7);
    const int row0 = cs0 >> 3, col0 = (cs0 & 7) * 8;
    const int row1 = cs1 >> 3, col1 = (cs1 & 7) * 8;

    int ibA[4][2], ibB[2][2];
#pragma unroll
    for (int s = 0; s < 4; ++s)
#pragma unroll
        for (int ks = 0; ks < 2; ++ks) {
            const int r = wr * 64 + s * 16 + l15;
            ibA[s][ks] = (r * 128 + ks * 64 + l4 * 16) ^ ((r & 7) << 4);
        }
#pragma unroll
    for (int s = 0; s < 2; ++s)
#pragma unroll
        for (int ks = 0; ks < 2; ++ks) {
            const int r = wc * 32 + s * 16 + l15;
            ibB[s][ks] = (r * 128 + ks * 64 + l4 * 16) ^ ((r & 7) << 4);
        }

    f32x4 acc[8][4] = {};
    short8 Aq[4][2], B0q[2][2], B1q[2][2];

    auto stageA = [&](int ro, int kk, int slot) {
        gld16(Ae + (size_t)(m0 + ro + row0) * K + (kk + col0), &lds[slot * 8192 + wave * 512]);
        gld16(Ae + (size_t)(m0 + ro + row1) * K + (kk + col1), &lds[slot * 8192 + 4096 + wave * 512]);
    };
    auto stageB = [&](int co, int kk, int slot) {
        gld16(Be + (size_t)(n0 + co + row0) * K + (kk + col0), &lds[slot * 8192 + wave * 512]);
        gld16(Be + (size_t)(n0 + co + row1) * K + (kk + col1), &lds[slot * 8192 + 4096 + wave * 512]);
    };

    stageA(0, 0, 0); stageB(0, 0, 1); stageB(128, 0, 2); stageA(128, 0, 3);
    stageA(0, 64, 4); stageB(0, 64, 5); stageB(128, 64, 6);
    asm volatile("s_waitcnt vmcnt(6)" ::: "memory");
    asm volatile("s_barrier" ::: "memory");

    const char* ldsc = (const char*)lds;
    for (int t = 0; t < NT; ++t) {
        const int sA0 = ((4 * t + 0) & 7) * 16384;
        const int sB0 = ((4 * t + 1) & 7) * 16384;
        const int sB1 = ((4 * t + 2) & 7) * 16384;
        const int sA1 = ((4 * t + 3) & 7) * 16384;

        // P0: read A0(8)+B0(4); stage (t+1,A1); MFMA Q(0,0)
#pragma unroll
        for (int s = 0; s < 4; ++s) {
            Aq[s][0] = *(const short8*)(ldsc + sA0 + ibA[s][0]);
            Aq[s][1] = *(const short8*)(ldsc + sA0 + ibA[s][1]);
        }
#pragma unroll
        for (int s = 0; s < 2; ++s) {
            B0q[s][0] = *(const short8*)(ldsc + sB0 + ibB[s][0]);
            B0q[s][1] = *(const short8*)(ldsc + sB0 + ibB[s][1]);
        }
        if (t + 1 < NT) stageA(128, (t + 1) * 64, (4 * t + 7) & 7);
        asm volatile("s_barrier" ::: "memory");
        asm volatile("s_waitcnt lgkmcnt(0)" ::: "memory");
        __builtin_amdgcn_sched_barrier(0);
        __builtin_amdgcn_s_setprio(1);
#pragma unroll
        for (int m = 0; m < 4; ++m)
#pragma unroll
            for (int n = 0; n < 2; ++n) {
                acc[m][n] = __builtin_amdgcn_mfma_f32_16x16x32_bf16(Aq[m][0], B0q[n][0], acc[m][n], 0, 0, 0);
                acc[m][n] = __builtin_amdgcn_mfma_f32_16x16x32_bf16(Aq[m][1], B0q[n][1], acc[m][n], 0, 0, 0);
            }
        __builtin_amdgcn_s_setprio(0);
        asm volatile("s_barrier" ::: "memory");

        // P1: read B1(4); stage (t+2,A0); MFMA Q(0,1)
#pragma unroll
        for (int s = 0; s < 2; ++s) {
            B1q[s][0] = *(const short8*)(ldsc + sB1 + ibB[s][0]);
            B1q[s][1] = *(const short8*)(ldsc + sB1 + ibB[s][1]);
        }
        if (t + 2 < NT) stageA(0, (t + 2) * 64, (4 * t + 8) & 7);
        asm volatile("s_barrier" ::: "memory");
        asm volatile("s_waitcnt lgkmcnt(0)" ::: "memory");
        __builtin_amdgcn_sched_barrier(0);
        __builtin_amdgcn_s_setprio(1);
#pragma unroll
        for (int m = 0; m < 4; ++m)
#pragma unroll
            for (int n = 0; n < 2; ++n) {
                acc[m][2 + n] = __builtin_amdgcn_mfma_f32_16x16x32_bf16(Aq[m][0], B1q[n][0], acc[m][2 + n], 0, 0, 0);
                acc[m][2 + n] = __builtin_amdgcn_mfma_f32_16x16x32_bf16(Aq[m][1], B1q[n][1], acc[m][2 + n], 0, 0, 0);
            }
        __builtin_amdgcn_s_setprio(0);
        asm volatile("s_barrier" ::: "memory");

        // P2: read A1(8); stage (t+2,B0); MFMA Q(1,1)
#pragma unroll
        for (int s = 0; s < 4; ++s) {
            Aq[s][0] = *(const short8*)(ldsc + sA1 + ibA[s][0]);
            Aq[s][1] = *(const short8*)(ldsc + sA1 + ibA[s][1]);
        }
        if (t + 2 < NT) stageB(0, (t + 2) * 64, (4 * t + 9) & 7);
        asm volatile("s_barrier" ::: "memory");
        asm volatile("s_waitcnt lgkmcnt(0)" ::: "memory");
        __builtin_amdgcn_sched_barrier(0);
        __builtin_amdgcn_s_setprio(1);
#pragma unroll
        for (int m = 0; m < 4; ++m)
#pragma unroll
            for (int n = 0; n < 2; ++n) {
                acc[4 + m][2 + n] = __builtin_amdgcn_mfma_f32_16x16x32_bf16(Aq[m][0], B1q[n][0], acc[4 + m][2 + n], 0, 0, 0);
                acc[4 + m][2 + n] = __builtin_amdgcn_mfma_f32_16x16x32_bf16(Aq[m][1], B1q[n][1], acc[4 + m][2 + n], 0, 0, 0);
            }
        __builtin_amdgcn_s_setprio(0);
        asm volatile("s_barrier" ::: "memory");

        // P3: stage (t+2,B1); MFMA Q(1,0); vmcnt
        if (t + 2 < NT) stageB(128, (t + 2) * 64, (4 * t + 10) & 7);
        asm volatile("s_barrier" ::: "memory");
        __builtin_amdgcn_s_setprio(1);
#pragma unroll
        for (int m = 0; m < 4; ++m)
#pragma unroll
            for (int n = 0; n < 2; ++n) {
                acc[4 + m][n] = __builtin_amdgcn_mfma_f32_16x16x32_bf16(Aq[m][0], B0q[n][0], acc[4 + m][n], 0, 0, 0);
                acc[4 + m][n] = __builtin_amdgcn_mfma_f32_16x16x32_bf16(Aq[m][1], B0q[n][1], acc[4 + m][n], 0, 0, 0);
            }
        __builtin_amdgcn_s_setprio(0);
        if (t < NT - 2)       asm volatile("s_waitcnt vmcnt(6)" ::: "memory");
        else if (t == NT - 2) asm volatile("s_waitcnt vmcnt(0)" ::: "memory");
        asm volatile("s_barrier" ::: "memory");
    }

    float* Ce = Cf + (size_t)e * TT * DIN;
#pragma unroll
    for (int fm = 0; fm < 8; ++fm) {
        const int row_b = (fm >> 2) * 128 + wr * 64 + (fm & 3) * 16 + l4 * 4;
#pragma unroll
        for (int fn = 0; fn < 4; ++fn) {
            const int col = n0 + (fn >> 1) * 128 + wc * 32 + (fn & 1) * 16 + l15;
#pragma unroll
            for (int j = 0; j < 4; ++j)
                Ce[(size_t)(m0 + row_b + j) * N + col] = acc[fm][fn][j];
        }
    }
}

// out[z][C][R] (bf16) = convert(in_z[z&7][R][C] (f32)); in_z = in0 (z<8) else
// in1. Output indexes linearly over z. 64x64 tiles.
__global__ __launch_bounds__(256) void transpose2_f32_bf16(
    const float* __restrict__ in0, const float* __restrict__ in1,
    unsigned short* __restrict__ out, int R, int C, size_t ies, size_t oes)
{
    const int z = blockIdx.z;
    const float* in = ((z < NEXP) ? in0 : in1) + (size_t)(z & 7) * ies;
    out += (size_t)z * oes;
    __shared__ unsigned short t[64][65];
    const int tid = threadIdx.x;
    const int lr = tid >> 4, lc = (tid & 15) * 4;
    const int r0 = blockIdx.y * 64, c0 = blockIdx.x * 64;
#pragma unroll
    for (int i = 0; i < 4; ++i) {
        const int row = lr + i * 16;
        const float4 v = *(const float4*)(in + (size_t)(r0 + row) * C + c0 + lc);
        t[row][lc + 0] = f2bf(v.x); t[row][lc + 1] = f2bf(v.y);
        t[row][lc + 2] = f2bf(v.z); t[row][lc + 3] = f2bf(v.w);
    }
    __syncthreads();
#pragma unroll
    for (int i = 0; i < 4; ++i) {
        const int crow = lr + i * 16;
        ushort4 wv;
        wv.x = t[lc + 0][crow]; wv.y = t[lc + 1][crow];
        wv.z = t[lc + 2][crow]; wv.w = t[lc + 3][crow];
        *(ushort4*)(out + (size_t)(c0 + crow) * R + r0 + lc) = wv;
    }
}

__global__ __launch_bounds__(256) void conv_f32_bf16(
    const float* __restrict__ in, unsigned short* __restrict__ out, int n4)
{
    int i = blockIdx.x * 256 + threadIdx.x;
    const int stride = gridDim.x * 256;
    for (; i < n4; i += stride) {
        const float4 v = ((const float4*)in)[i];
        ushort4 wv;
        wv.x = f2bf(v.x); wv.y = f2bf(v.y); wv.z = f2bf(v.z); wv.w = f2bf(v.w);
        ((ushort4*)out)[i] = wv;
    }
}

extern "C" void kernel_launch(void* const* d_in, const int* in_sizes, int n_in,
                              void* d_out, int out_size, void* d_ws, size_t ws_size,
                              hipStream_t stream)
{
    const float* x  = (const float*)d_in[0];  // [E,T,DIN]
    const float* wg = (const float*)d_in[1];  // [E,DIN,DH]
    const float* wd = (const float*)d_in[2];  // [E,DIN,DH]
    const float* wu = (const float*)d_in[3];  // [E,DH,DIN]
    float* out = (float*)d_out;               // [E,T,DIN] fp32

    const size_t XSZ = (size_t)TT * DIN;      // per-expert X elems
    const size_t WSZ = (size_t)DIN * DH;      // per-expert weight elems
    unsigned short* xb  = (unsigned short*)d_ws;      // [E] X bf16      67 MB
    unsigned short* wgt = xb  + (size_t)NEXP * XSZ;   // [E] WgT / WuT  185 MB
    unsigned short* wdt = wgt + (size_t)NEXP * WSZ;   // [E] WdT        185 MB
    unsigned short* hb  = wdt + (size_t)NEXP * WSZ;   // [E] H          185 MB
    // total ws: 622 MB

    // X -> bf16 (all experts)
    conv_f32_bf16<<<4096, 256, 0, stream>>>(x, xb, (int)(NEXP * XSZ / 4));
    // WgT + WdT in ONE launch: z in [0,16) covers wgt then wdt (contiguous).
    transpose2_f32_bf16<<<dim3(DH / 64, DIN / 64, NEXP * 2), 256, 0, stream>>>(
        wg, wd, wgt, DIN, DH, WSZ, WSZ);
    // H = silu(X*Wg) * (X*Wd)   [E][T][DH]  — 128x128, 2 blocks/CU
    gemm_gu<<<NEXP * (TT / 128) * (DH / 128), 256, 0, stream>>>(xb, wgt, wdt, hb);
    // WuT: [E][DIN][DH] K-major (reuse WgT region)
    transpose2_f32_bf16<<<dim3(DIN / 64, DH / 64, NEXP), 256, 0, stream>>>(
        wu, wu, wgt, DH, DIN, WSZ, WSZ);
    // Out = H * Wu   [E][T][DIN] fp32
    gemm_out<<<NEXP * (TT / 256) * (DIN / 256), 512, 0, stream>>>(hb, wgt, out);
}

// Round 12
// 1258.035 us; speedup vs baseline: 1.0289x; 1.0289x over previous
//
#include <hip/hip_runtime.h>
#include <hip/hip_bf16.h>

// Grouped SwiGLU experts: E=8, T=2048, D_IN=2048, D_H=5632. FP32 in/out.
// r16 == r13 (best verified: 1258.0 us; gu ~708, MfmaUtil 49, 0 bank
// conflicts). r14/r15 (2 blocks/CU) raised MfmaUtil to 52 but cost more in
// X over-fetch (+340 MB HBM) and a reproducible ~60 us downstream slowdown.
// Final state: r5 GEMM pair + merged Wg/Wd transpose.

#define NEXP 8
#define TT   2048
#define DIN  2048
#define DH   5632

using short8 = __attribute__((ext_vector_type(8))) short;   // 8 x bf16
using f32x4  = __attribute__((ext_vector_type(4))) float;   // MFMA acc

static __device__ __forceinline__ unsigned short f2bf(float f) {
    unsigned int i = __float_as_uint(f);
    return (unsigned short)((i + 0x7FFFu + ((i >> 16) & 1u)) >> 16);  // RNE
}
static __device__ __forceinline__ void gld16(const void* g, void* l) {
    __builtin_amdgcn_global_load_lds(
        (const __attribute__((address_space(1))) void*)g,
        (__attribute__((address_space(3))) void*)l, 16, 0, 0);
}

// ---------------------------------------------------------------------------
// Fused G/U GEMM: computes G = X*WgT^T, U = X*WdT^T, writes H = silu(G)*U.
// Tile 256(M) x 128(N), BK=64. 8 waves as 2M x 4N per quadrant (64x32 each).
// Quadrant schedule: P0: read A0(8)+Gq(4), MFMA G-top; P1: read Dq(4),
// MFMA U-top; P2: read A1(8), MFMA U-bot; P3: no reads, MFMA G-bot.
// Ring-8 16KB halves, vmcnt(6)/tile. Swizzle: read byte ^= (row&7)<<4;
// stage pre-applies c ^= (c>>3)&7. Block map: e = bid&7 (XCD), w = bid>>3.
// ---------------------------------------------------------------------------
__global__ __launch_bounds__(512, 2) void gemm_gu(
    const unsigned short* __restrict__ Xb,   // [E][T][DIN] bf16
    const unsigned short* __restrict__ Wgt,  // [E][DH][DIN] bf16 (K-major)
    const unsigned short* __restrict__ Wdt,  // [E][DH][DIN] bf16
    unsigned short* __restrict__ Hb)         // [E][T][DH] bf16
{
    __shared__ __align__(16) unsigned short lds[65536];  // 128 KB

    const int tid  = threadIdx.x;
    const int wave = tid >> 6, lane = tid & 63;
    const int l15 = lane & 15, l4 = lane >> 4;
    const int wr = wave >> 2, wc = wave & 3;     // 2M x 4N wave grid

    const int orig = blockIdx.x;                 // 2816 blocks = 8 * 352
    const int e    = orig & 7;                   // expert == XCD
    const int w    = orig >> 3;                  // [0,352)
    const int r32  = w & 31;
    const int m0   = (r32 & 7) * 256;            // 8 M-blocks
    const int n0   = ((w >> 5) * 4 + (r32 >> 3)) * 128;  // 44 N-blocks

    const int K = DIN, NT = DIN >> 6;            // NT = 32

    const unsigned short* Ae = Xb  + (size_t)e * TT * DIN;              // [T][K]
    const unsigned short* Gp = Wgt + (size_t)e * DH * DIN + (size_t)n0 * K;
    const unsigned short* Dp = Wdt + (size_t)e * DH * DIN + (size_t)n0 * K;

    // Stage-side: chunk c of 1024 16B-chunks/half; src pos cs = c ^ ((c>>3)&7).
    const int c0 = tid, c1 = 512 + tid;
    const int cs0 = c0 ^ ((c0 >> 3) & 7), cs1 = c1 ^ ((c1 >> 3) & 7);
    const int row0 = cs0 >> 3, col0 = (cs0 & 7) * 8;
    const int row1 = cs1 >> 3, col1 = (cs1 & 7) * 8;

    // Read-side swizzled byte offsets within a 16KB half.
    int ibA[4][2], ibB[2][2];
#pragma unroll
    for (int s = 0; s < 4; ++s)
#pragma unroll
        for (int ks = 0; ks < 2; ++ks) {
            const int r = wr * 64 + s * 16 + l15;
            ibA[s][ks] = (r * 128 + ks * 64 + l4 * 16) ^ ((r & 7) << 4);
        }
#pragma unroll
    for (int s = 0; s < 2; ++s)
#pragma unroll
        for (int ks = 0; ks < 2; ++ks) {
            const int r = wc * 32 + s * 16 + l15;
            ibB[s][ks] = (r * 128 + ks * 64 + l4 * 16) ^ ((r & 7) << 4);
        }

    // acc[0..3][0..1] = G-top, acc[0..3][2..3] = U-top,
    // acc[4..7][2..3] = U-bot, acc[4..7][0..1] = G-bot.
    f32x4 acc[8][4] = {};
    short8 Aq[4][2], Gq[2][2], Dq[2][2];

    auto stageA = [&](int ro, int kk, int slot) {
        gld16(Ae + (size_t)(m0 + ro + row0) * K + (kk + col0), &lds[slot * 8192 + wave * 512]);
        gld16(Ae + (size_t)(m0 + ro + row1) * K + (kk + col1), &lds[slot * 8192 + 4096 + wave * 512]);
    };
    auto stageW = [&](const unsigned short* p, int kk, int slot) {
        gld16(p + (size_t)row0 * K + (kk + col0), &lds[slot * 8192 + wave * 512]);
        gld16(p + (size_t)row1 * K + (kk + col1), &lds[slot * 8192 + 4096 + wave * 512]);
    };

    // Prologue: t0 {A0,G,D,A1} -> slots 0..3; t1 {A0,G,D} -> slots 4..6.
    stageA(0, 0, 0);  stageW(Gp, 0, 1);  stageW(Dp, 0, 2);  stageA(128, 0, 3);
    stageA(0, 64, 4); stageW(Gp, 64, 5); stageW(Dp, 64, 6);
    asm volatile("s_waitcnt vmcnt(6)" ::: "memory");
    asm volatile("s_barrier" ::: "memory");

    const char* ldsc = (const char*)lds;
    for (int t = 0; t < NT; ++t) {
        const int sA0 = ((4 * t + 0) & 7) * 16384;
        const int sG  = ((4 * t + 1) & 7) * 16384;
        const int sD  = ((4 * t + 2) & 7) * 16384;
        const int sA1 = ((4 * t + 3) & 7) * 16384;

        // P0: read A0(8)+Gq(4); stage (t+1,A1); MFMA G-top
#pragma unroll
        for (int s = 0; s < 4; ++s) {
            Aq[s][0] = *(const short8*)(ldsc + sA0 + ibA[s][0]);
            Aq[s][1] = *(const short8*)(ldsc + sA0 + ibA[s][1]);
        }
#pragma unroll
        for (int s = 0; s < 2; ++s) {
            Gq[s][0] = *(const short8*)(ldsc + sG + ibB[s][0]);
            Gq[s][1] = *(const short8*)(ldsc + sG + ibB[s][1]);
        }
        if (t + 1 < NT) stageA(128, (t + 1) * 64, (4 * t + 7) & 7);
        asm volatile("s_barrier" ::: "memory");
        asm volatile("s_waitcnt lgkmcnt(0)" ::: "memory");
        __builtin_amdgcn_sched_barrier(0);
        __builtin_amdgcn_s_setprio(1);
#pragma unroll
        for (int m = 0; m < 4; ++m)
#pragma unroll
            for (int n = 0; n < 2; ++n) {
                acc[m][n] = __builtin_amdgcn_mfma_f32_16x16x32_bf16(Aq[m][0], Gq[n][0], acc[m][n], 0, 0, 0);
                acc[m][n] = __builtin_amdgcn_mfma_f32_16x16x32_bf16(Aq[m][1], Gq[n][1], acc[m][n], 0, 0, 0);
            }
        __builtin_amdgcn_s_setprio(0);
        asm volatile("s_barrier" ::: "memory");

        // P1: read Dq(4); stage (t+2,A0); MFMA U-top
#pragma unroll
        for (int s = 0; s < 2; ++s) {
            Dq[s][0] = *(const short8*)(ldsc + sD + ibB[s][0]);
            Dq[s][1] = *(const short8*)(ldsc + sD + ibB[s][1]);
        }
        if (t + 2 < NT) stageA(0, (t + 2) * 64, (4 * t + 8) & 7);
        asm volatile("s_barrier" ::: "memory");
        asm volatile("s_waitcnt lgkmcnt(0)" ::: "memory");
        __builtin_amdgcn_sched_barrier(0);
        __builtin_amdgcn_s_setprio(1);
#pragma unroll
        for (int m = 0; m < 4; ++m)
#pragma unroll
            for (int n = 0; n < 2; ++n) {
                acc[m][2 + n] = __builtin_amdgcn_mfma_f32_16x16x32_bf16(Aq[m][0], Dq[n][0], acc[m][2 + n], 0, 0, 0);
                acc[m][2 + n] = __builtin_amdgcn_mfma_f32_16x16x32_bf16(Aq[m][1], Dq[n][1], acc[m][2 + n], 0, 0, 0);
            }
        __builtin_amdgcn_s_setprio(0);
        asm volatile("s_barrier" ::: "memory");

        // P2: read A1(8); stage (t+2,G); MFMA U-bot
#pragma unroll
        for (int s = 0; s < 4; ++s) {
            Aq[s][0] = *(const short8*)(ldsc + sA1 + ibA[s][0]);
            Aq[s][1] = *(const short8*)(ldsc + sA1 + ibA[s][1]);
        }
        if (t + 2 < NT) stageW(Gp, (t + 2) * 64, (4 * t + 9) & 7);
        asm volatile("s_barrier" ::: "memory");
        asm volatile("s_waitcnt lgkmcnt(0)" ::: "memory");
        __builtin_amdgcn_sched_barrier(0);
        __builtin_amdgcn_s_setprio(1);
#pragma unroll
        for (int m = 0; m < 4; ++m)
#pragma unroll
            for (int n = 0; n < 2; ++n) {
                acc[4 + m][2 + n] = __builtin_amdgcn_mfma_f32_16x16x32_bf16(Aq[m][0], Dq[n][0], acc[4 + m][2 + n], 0, 0, 0);
                acc[4 + m][2 + n] = __builtin_amdgcn_mfma_f32_16x16x32_bf16(Aq[m][1], Dq[n][1], acc[4 + m][2 + n], 0, 0, 0);
            }
        __builtin_amdgcn_s_setprio(0);
        asm volatile("s_barrier" ::: "memory");

        // P3: stage (t+2,D); MFMA G-bot (register-only); vmcnt
        if (t + 2 < NT) stageW(Dp, (t + 2) * 64, (4 * t + 10) & 7);
        asm volatile("s_barrier" ::: "memory");
        __builtin_amdgcn_s_setprio(1);
#pragma unroll
        for (int m = 0; m < 4; ++m)
#pragma unroll
            for (int n = 0; n < 2; ++n) {
                acc[4 + m][n] = __builtin_amdgcn_mfma_f32_16x16x32_bf16(Aq[m][0], Gq[n][0], acc[4 + m][n], 0, 0, 0);
                acc[4 + m][n] = __builtin_amdgcn_mfma_f32_16x16x32_bf16(Aq[m][1], Gq[n][1], acc[4 + m][n], 0, 0, 0);
            }
        __builtin_amdgcn_s_setprio(0);
        if (t < NT - 2)       asm volatile("s_waitcnt vmcnt(6)" ::: "memory");
        else if (t == NT - 2) asm volatile("s_waitcnt vmcnt(0)" ::: "memory");
        asm volatile("s_barrier" ::: "memory");
    }

    // Epilogue: H = silu(G) * U, bf16. C/D: col = lane&15, row = (lane>>4)*4+j.
    unsigned short* He = Hb + (size_t)e * TT * DH;
#pragma unroll
    for (int fm = 0; fm < 8; ++fm) {
        const int row_b = m0 + (fm >> 2) * 128 + wr * 64 + (fm & 3) * 16 + l4 * 4;
#pragma unroll
        for (int nr = 0; nr < 2; ++nr) {
            const int col = n0 + wc * 32 + nr * 16 + l15;
#pragma unroll
            for (int j = 0; j < 4; ++j) {
                const float g = acc[fm][nr][j];
                const float u = acc[fm][2 + nr][j];
                const float h = g / (1.f + __expf(-g)) * u;
                He[(size_t)(row_b + j) * DH + col] = f2bf(h);
            }
        }
    }
}

// ---------------------------------------------------------------------------
// Out-GEMM: Out = H * WuT^T, fp32 out. 256x256, BK=64, 8 waves (2Mx4N),
// ring-8 halves {A0,B0,B1,A1}, vmcnt(6)/K-tile.
// Block map: e = bid&7, w = bid>>3 in [0,64): chunks of 8M x 4N.
// ---------------------------------------------------------------------------
__global__ __launch_bounds__(512, 2) void gemm_out(
    const unsigned short* __restrict__ Ab,   // H [E][T][DH] bf16
    const unsigned short* __restrict__ Btb,  // WuT [E][DIN][DH] bf16
    float* __restrict__ Cf)                  // [E][T][DIN] fp32
{
    __shared__ __align__(16) unsigned short lds[65536];

    const int tid  = threadIdx.x;
    const int wave = tid >> 6, lane = tid & 63;
    const int l15 = lane & 15, l4 = lane >> 4;
    const int wr = wave >> 2, wc = wave & 3;     // 2M x 4N

    const int orig = blockIdx.x;                 // 512 = 8 * 64
    const int e    = orig & 7;
    const int w    = orig >> 3;                  // [0,64)
    const int r32  = w & 31;
    const int m0   = (r32 & 7) * 256;
    const int n0   = ((w >> 5) * 4 + (r32 >> 3)) * 256;

    const int N = DIN, K = DH, NT = K >> 6;      // NT = 88
    const unsigned short* Ae = Ab  + (size_t)e * TT * DH;
    const unsigned short* Be = Btb + (size_t)e * DIN * DH;

    const int c0 = tid, c1 = 512 + tid;
    const int cs0 = c0 ^ ((c0 >> 3) & 7), cs1 = c1 ^ ((c1 >> 3) & 7);
    const int row0 = cs0 >> 3, col0 = (cs0 & 7) * 8;
    const int row1 = cs1 >> 3, col1 = (cs1 & 7) * 8;

    int ibA[4][2], ibB[2][2];
#pragma unroll
    for (int s = 0; s < 4; ++s)
#pragma unroll
        for (int ks = 0; ks < 2; ++ks) {
            const int r = wr * 64 + s * 16 + l15;
            ibA[s][ks] = (r * 128 + ks * 64 + l4 * 16) ^ ((r & 7) << 4);
        }
#pragma unroll
    for (int s = 0; s < 2; ++s)
#pragma unroll
        for (int ks = 0; ks < 2; ++ks) {
            const int r = wc * 32 + s * 16 + l15;
            ibB[s][ks] = (r * 128 + ks * 64 + l4 * 16) ^ ((r & 7) << 4);
        }

    f32x4 acc[8][4] = {};
    short8 Aq[4][2], B0q[2][2], B1q[2][2];

    auto stageA = [&](int ro, int kk, int slot) {
        gld16(Ae + (size_t)(m0 + ro + row0) * K + (kk + col0), &lds[slot * 8192 + wave * 512]);
        gld16(Ae + (size_t)(m0 + ro + row1) * K + (kk + col1), &lds[slot * 8192 + 4096 + wave * 512]);
    };
    auto stageB = [&](int co, int kk, int slot) {
        gld16(Be + (size_t)(n0 + co + row0) * K + (kk + col0), &lds[slot * 8192 + wave * 512]);
        gld16(Be + (size_t)(n0 + co + row1) * K + (kk + col1), &lds[slot * 8192 + 4096 + wave * 512]);
    };

    stageA(0, 0, 0); stageB(0, 0, 1); stageB(128, 0, 2); stageA(128, 0, 3);
    stageA(0, 64, 4); stageB(0, 64, 5); stageB(128, 64, 6);
    asm volatile("s_waitcnt vmcnt(6)" ::: "memory");
    asm volatile("s_barrier" ::: "memory");

    const char* ldsc = (const char*)lds;
    for (int t = 0; t < NT; ++t) {
        const int sA0 = ((4 * t + 0) & 7) * 16384;
        const int sB0 = ((4 * t + 1) & 7) * 16384;
        const int sB1 = ((4 * t + 2) & 7) * 16384;
        const int sA1 = ((4 * t + 3) & 7) * 16384;

        // P0: read A0(8)+B0(4); stage (t+1,A1); MFMA Q(0,0)
#pragma unroll
        for (int s = 0; s < 4; ++s) {
            Aq[s][0] = *(const short8*)(ldsc + sA0 + ibA[s][0]);
            Aq[s][1] = *(const short8*)(ldsc + sA0 + ibA[s][1]);
        }
#pragma unroll
        for (int s = 0; s < 2; ++s) {
            B0q[s][0] = *(const short8*)(ldsc + sB0 + ibB[s][0]);
            B0q[s][1] = *(const short8*)(ldsc + sB0 + ibB[s][1]);
        }
        if (t + 1 < NT) stageA(128, (t + 1) * 64, (4 * t + 7) & 7);
        asm volatile("s_barrier" ::: "memory");
        asm volatile("s_waitcnt lgkmcnt(0)" ::: "memory");
        __builtin_amdgcn_sched_barrier(0);
        __builtin_amdgcn_s_setprio(1);
#pragma unroll
        for (int m = 0; m < 4; ++m)
#pragma unroll
            for (int n = 0; n < 2; ++n) {
                acc[m][n] = __builtin_amdgcn_mfma_f32_16x16x32_bf16(Aq[m][0], B0q[n][0], acc[m][n], 0, 0, 0);
                acc[m][n] = __builtin_amdgcn_mfma_f32_16x16x32_bf16(Aq[m][1], B0q[n][1], acc[m][n], 0, 0, 0);
            }
        __builtin_amdgcn_s_setprio(0);
        asm volatile("s_barrier" ::: "memory");

        // P1: read B1(4); stage (t+2,A0); MFMA Q(0,1)
#pragma unroll
        for (int s = 0; s < 2; ++s) {
            B1q[s][0] = *(const short8*)(ldsc + sB1 + ibB[s][0]);
            B1q[s][1] = *(const short8*)(ldsc + sB1 + ibB[s][1]);
        }
        if (t + 2 < NT) stageA(0, (t + 2) * 64, (4 * t + 8) & 7);
        asm volatile("s_barrier" ::: "memory");
        asm volatile("s_waitcnt lgkmcnt(0)" ::: "memory");
        __builtin_amdgcn_sched_barrier(0);
        __builtin_amdgcn_s_setprio(1);
#pragma unroll
        for (int m = 0; m < 4; ++m)
#pragma unroll
            for (int n = 0; n < 2; ++n) {
                acc[m][2 + n] = __builtin_amdgcn_mfma_f32_16x16x32_bf16(Aq[m][0], B1q[n][0], acc[m][2 + n], 0, 0, 0);
                acc[m][2 + n] = __builtin_amdgcn_mfma_f32_16x16x32_bf16(Aq[m][1], B1q[n][1], acc[m][2 + n], 0, 0, 0);
            }
        __builtin_amdgcn_s_setprio(0);
        asm volatile("s_barrier" ::: "memory");

        // P2: read A1(8); stage (t+2,B0); MFMA Q(1,1)
#pragma unroll
        for (int s = 0; s < 4; ++s) {
            Aq[s][0] = *(const short8*)(ldsc + sA1 + ibA[s][0]);
            Aq[s][1] = *(const short8*)(ldsc + sA1 + ibA[s][1]);
        }
        if (t + 2 < NT) stageB(0, (t + 2) * 64, (4 * t + 9) & 7);
        asm volatile("s_barrier" ::: "memory");
        asm volatile("s_waitcnt lgkmcnt(0)" ::: "memory");
        __builtin_amdgcn_sched_barrier(0);
        __builtin_amdgcn_s_setprio(1);
#pragma unroll
        for (int m = 0; m < 4; ++m)
#pragma unroll
            for (int n = 0; n < 2; ++n) {
                acc[4 + m][2 + n] = __builtin_amdgcn_mfma_f32_16x16x32_bf16(Aq[m][0], B1q[n][0], acc[4 + m][2 + n], 0, 0, 0);
                acc[4 + m][2 + n] = __builtin_amdgcn_mfma_f32_16x16x32_bf16(Aq[m][1], B1q[n][1], acc[4 + m][2 + n], 0, 0, 0);
            }
        __builtin_amdgcn_s_setprio(0);
        asm volatile("s_barrier" ::: "memory");

        // P3: stage (t+2,B1); MFMA Q(1,0); vmcnt
        if (t + 2 < NT) stageB(128, (t + 2) * 64, (4 * t + 10) & 7);
        asm volatile("s_barrier" ::: "memory");
        __builtin_amdgcn_s_setprio(1);
#pragma unroll
        for (int m = 0; m < 4; ++m)
#pragma unroll
            for (int n = 0; n < 2; ++n) {
                acc[4 + m][n] = __builtin_amdgcn_mfma_f32_16x16x32_bf16(Aq[m][0], B0q[n][0], acc[4 + m][n], 0, 0, 0);
                acc[4 + m][n] = __builtin_amdgcn_mfma_f32_16x16x32_bf16(Aq[m][1], B0q[n][1], acc[4 + m][n], 0, 0, 0);
            }
        __builtin_amdgcn_s_setprio(0);
        if (t < NT - 2)       asm volatile("s_waitcnt vmcnt(6)" ::: "memory");
        else if (t == NT - 2) asm volatile("s_waitcnt vmcnt(0)" ::: "memory");
        asm volatile("s_barrier" ::: "memory");
    }

    float* Ce = Cf + (size_t)e * TT * DIN;
#pragma unroll
    for (int fm = 0; fm < 8; ++fm) {
        const int row_b = (fm >> 2) * 128 + wr * 64 + (fm & 3) * 16 + l4 * 4;
#pragma unroll
        for (int fn = 0; fn < 4; ++fn) {
            const int col = n0 + (fn >> 1) * 128 + wc * 32 + (fn & 1) * 16 + l15;
#pragma unroll
            for (int j = 0; j < 4; ++j)
                Ce[(size_t)(m0 + row_b + j) * N + col] = acc[fm][fn][j];
        }
    }
}

// out[z][C][R] (bf16) = convert(in_z[z&7][R][C] (f32)); in_z = in0 (z<8) else
// in1. Output indexes linearly over z. 64x64 tiles.
__global__ __launch_bounds__(256) void transpose2_f32_bf16(
    const float* __restrict__ in0, const float* __restrict__ in1,
    unsigned short* __restrict__ out, int R, int C, size_t ies, size_t oes)
{
    const int z = blockIdx.z;
    const float* in = ((z < NEXP) ? in0 : in1) + (size_t)(z & 7) * ies;
    out += (size_t)z * oes;
    __shared__ unsigned short t[64][65];
    const int tid = threadIdx.x;
    const int lr = tid >> 4, lc = (tid & 15) * 4;
    const int r0 = blockIdx.y * 64, c0 = blockIdx.x * 64;
#pragma unroll
    for (int i = 0; i < 4; ++i) {
        const int row = lr + i * 16;
        const float4 v = *(const float4*)(in + (size_t)(r0 + row) * C + c0 + lc);
        t[row][lc + 0] = f2bf(v.x); t[row][lc + 1] = f2bf(v.y);
        t[row][lc + 2] = f2bf(v.z); t[row][lc + 3] = f2bf(v.w);
    }
    __syncthreads();
#pragma unroll
    for (int i = 0; i < 4; ++i) {
        const int crow = lr + i * 16;
        ushort4 wv;
        wv.x = t[lc + 0][crow]; wv.y = t[lc + 1][crow];
        wv.z = t[lc + 2][crow]; wv.w = t[lc + 3][crow];
        *(ushort4*)(out + (size_t)(c0 + crow) * R + r0 + lc) = wv;
    }
}

__global__ __launch_bounds__(256) void conv_f32_bf16(
    const float* __restrict__ in, unsigned short* __restrict__ out, int n4)
{
    int i = blockIdx.x * 256 + threadIdx.x;
    const int stride = gridDim.x * 256;
    for (; i < n4; i += stride) {
        const float4 v = ((const float4*)in)[i];
        ushort4 wv;
        wv.x = f2bf(v.x); wv.y = f2bf(v.y); wv.z = f2bf(v.z); wv.w = f2bf(v.w);
        ((ushort4*)out)[i] = wv;
    }
}

extern "C" void kernel_launch(void* const* d_in, const int* in_sizes, int n_in,
                              void* d_out, int out_size, void* d_ws, size_t ws_size,
                              hipStream_t stream)
{
    const float* x  = (const float*)d_in[0];  // [E,T,DIN]
    const float* wg = (const float*)d_in[1];  // [E,DIN,DH]
    const float* wd = (const float*)d_in[2];  // [E,DIN,DH]
    const float* wu = (const float*)d_in[3];  // [E,DH,DIN]
    float* out = (float*)d_out;               // [E,T,DIN] fp32

    const size_t XSZ = (size_t)TT * DIN;      // per-expert X elems
    const size_t WSZ = (size_t)DIN * DH;      // per-expert weight elems
    unsigned short* xb  = (unsigned short*)d_ws;      // [E] X bf16      67 MB
    unsigned short* wgt = xb  + (size_t)NEXP * XSZ;   // [E] WgT / WuT  185 MB
    unsigned short* wdt = wgt + (size_t)NEXP * WSZ;   // [E] WdT        185 MB
    unsigned short* hb  = wdt + (size_t)NEXP * WSZ;   // [E] H          185 MB
    // total ws: 622 MB

    // X -> bf16 (all experts)
    conv_f32_bf16<<<4096, 256, 0, stream>>>(x, xb, (int)(NEXP * XSZ / 4));
    // WgT + WdT in ONE launch: z in [0,16) covers wgt then wdt (contiguous).
    transpose2_f32_bf16<<<dim3(DH / 64, DIN / 64, NEXP * 2), 256, 0, stream>>>(
        wg, wd, wgt, DIN, DH, WSZ, WSZ);
    // H = silu(X*Wg) * (X*Wd)   [E][T][DH]  — fused dual-acc GEMM
    gemm_gu<<<NEXP * (TT / 256) * (DH / 128), 512, 0, stream>>>(xb, wgt, wdt, hb);
    // WuT: [E][DIN][DH] K-major (reuse WgT region)
    transpose2_f32_bf16<<<dim3(DIN / 64, DH / 64, NEXP), 256, 0, stream>>>(
        wu, wu, wgt, DH, DIN, WSZ, WSZ);
    // Out = H * Wu   [E][T][DIN] fp32
    gemm_out<<<NEXP * (TT / 256) * (DIN / 256), 512, 0, stream>>>(hb, wgt, out);
}